// Round 1
// baseline (83.897 us; speedup 1.0000x reference)
//
#include <hip/hip_runtime.h>

// EvenLayer min-sum check-node update.
// Structural decode of the reference's inf_mask:
//   edge e in [0, 3600); check(e) = e % 600; each check has 6 edges, stride 600.
//   (The lexsort in _build_inf_mask is the identity: 3i % 600 is a multiple of
//    3 <= 597, so each variable's check triple (m, m+1, m+2) never wraps and is
//    already sorted.)
// out[b, e] = loo_sign(b, e) * max(loo_min(b, e) - bias[e], 0)
// where loo_* are computed over the 5 OTHER edges of e's check.
// inf_mask (d_in[2], 52 MB) is never read.

#define N_CHK 600
#define D_PER 6      // edges per check = 3600 / 600
#define E_TOT 3600
#define BATCH 8

__global__ __launch_bounds__(256) void evenlayer_kernel(
        const float* __restrict__ x,      // [BATCH, E_TOT]
        const float* __restrict__ bias,   // [E_TOT]
        float* __restrict__ out) {        // [BATCH, E_TOT]
    int t = blockIdx.x * blockDim.x + threadIdx.x;   // 0 .. 4799
    if (t >= BATCH * N_CHK) return;
    int b = t / N_CHK;
    int r = t - b * N_CHK;                // check index; lanes r consecutive -> coalesced

    const float* xb = x + b * E_TOT;
    float v[D_PER];
#pragma unroll
    for (int k = 0; k < D_PER; ++k) v[k] = xb[r + N_CHK * k];

    // two smallest |v|, argmin, negative count, zero count
    float min1 = INFINITY, min2 = INFINITY;
    int amin = 0, negc = 0, zeroc = 0;
#pragma unroll
    for (int k = 0; k < D_PER; ++k) {
        float av = fabsf(v[k]);
        negc  += (v[k] < 0.0f);
        zeroc += (v[k] == 0.0f);
        if (av < min1) { min2 = min1; min1 = av; amin = k; }
        else if (av < min2) { min2 = av; }
    }

    float* ob = out + b * E_TOT;
#pragma unroll
    for (int k = 0; k < D_PER; ++k) {
        int e = r + N_CHK * k;
        float loo_min = (k == amin) ? min2 : min1;      // tie-safe: min2==min1 on ties
        int   nl = negc  - (v[k] < 0.0f);
        int   zl = zeroc - (v[k] == 0.0f);
        float s  = (zl > 0) ? 0.0f : ((nl & 1) ? -1.0f : 1.0f);
        ob[e] = s * fmaxf(loo_min - bias[e], 0.0f);
    }
}

extern "C" void kernel_launch(void* const* d_in, const int* in_sizes, int n_in,
                              void* d_out, int out_size, void* d_ws, size_t ws_size,
                              hipStream_t stream) {
    const float* x    = (const float*)d_in[0];   // inputs [8, 3600] fp32
    const float* bias = (const float*)d_in[1];   // bias   [1, 3600] fp32
    // d_in[2] = inf_mask: structure known analytically, never read.
    float* out = (float*)d_out;                  // [8, 3600] fp32

    const int total   = BATCH * N_CHK;           // 4800 threads
    const int block   = 256;
    const int grid    = (total + block - 1) / block;  // 19
    evenlayer_kernel<<<grid, block, 0, stream>>>(x, bias, out);
}